// Round 7
// baseline (17745.276 us; speedup 1.0000x reference)
//
#include <hip/hip_runtime.h>
#include <hip/hip_bf16.h>
#include <stdint.h>

#define DIMS 2048
#define SEQ  4096
#define NBLK 256   // persistent blocks (one per CU)
#define RPB  8     // rows of W_hh per block
#define NW   1024  // tagged words per slot (= DIMS/2)
#define CHUNK 16   // steps per Z/X/out LDS batch

typedef unsigned long long ull;
typedef unsigned int v4u __attribute__((ext_vector_type(4)));

// ---------- helpers ----------
__device__ __forceinline__ unsigned pk_bf16(float a, float b) {
  // round-to-nearest-even bf16, packed (a -> low16, b -> high16)
  unsigned ua = __float_as_uint(a);
  ua += 0x7fffu + ((ua >> 16) & 1u);
  unsigned ub = __float_as_uint(b);
  ub += 0x7fffu + ((ub >> 16) & 1u);
  return (ua >> 16) | (ub & 0xffff0000u);
}
__device__ __forceinline__ float bflo(unsigned u) { return __uint_as_float(u << 16); }
__device__ __forceinline__ float bfhi(unsigned u) { return __uint_as_float(u & 0xffff0000u); }

// ---------- Kernel A: Z = X @ W_hi^T + b  (fp32, written into d_out) ----------
__global__ __launch_bounds__(256) void gemm_z(const float* __restrict__ X,
                                              const float* __restrict__ W,
                                              const float* __restrict__ bias,
                                              float* __restrict__ Z) {
  __shared__ float xs[64][33];
  __shared__ float ws[64][33];
  const int tid = threadIdx.x;
  const int tx = tid & 15;
  const int ty = tid >> 4;
  const int s0 = blockIdx.x * 64;
  const int d0 = blockIdx.y * 64;

  float acc[4][4] = {};

  for (int k0 = 0; k0 < DIMS; k0 += 32) {
#pragma unroll
    for (int i = 0; i < 2; ++i) {
      int idx = tid + i * 256;
      int r = idx >> 3;
      int c = (idx & 7) << 2;
      float4 xv = *(const float4*)&X[(size_t)(s0 + r) * DIMS + k0 + c];
      xs[r][c] = xv.x; xs[r][c + 1] = xv.y; xs[r][c + 2] = xv.z; xs[r][c + 3] = xv.w;
      float4 wv = *(const float4*)&W[(size_t)(d0 + r) * DIMS + k0 + c];
      ws[r][c] = wv.x; ws[r][c + 1] = wv.y; ws[r][c + 2] = wv.z; ws[r][c + 3] = wv.w;
    }
    __syncthreads();
#pragma unroll
    for (int k = 0; k < 32; ++k) {
      float a_[4], b_[4];
#pragma unroll
      for (int i = 0; i < 4; ++i) a_[i] = xs[ty * 4 + i][k];
#pragma unroll
      for (int j = 0; j < 4; ++j) b_[j] = ws[tx * 4 + j][k];
#pragma unroll
      for (int i = 0; i < 4; ++i)
#pragma unroll
        for (int j = 0; j < 4; ++j) acc[i][j] += a_[i] * b_[j];
    }
    __syncthreads();
  }

  const float4 bv = *(const float4*)&bias[d0 + tx * 4];
#pragma unroll
  for (int i = 0; i < 4; ++i) {
    float4 o;
    o.x = acc[i][0] + bv.x; o.y = acc[i][1] + bv.y;
    o.z = acc[i][2] + bv.z; o.w = acc[i][3] + bv.w;
    *(float4*)&Z[(size_t)(s0 + ty * 4 + i) * DIMS + d0 + tx * 4] = o;
  }
}

// ---------- Kernel B: persistent recurrence, tagged words + chunked I/O ----------
// Per STEP the only VMEM is: 2 poll loads (32B tagged h words, sc0 sc1) and
// 1 publish store per wave. Z/X inputs and residual outputs move through LDS
// in CHUNK-step batches at chunk boundaries (burst loads/stores by 96 threads),
// so the per-step poll's vmcnt(0) never waits on an HBM round trip.
// Tagged protocol identical to R5 (passed): word g of slot t&1 gets tag t+1;
// consumer thread tid polls words [4*tid,4*tid+4) of slot (t+1)&1 for tag t.
__global__ __launch_bounds__(256) void rnn_seq(const float* __restrict__ X,
                                               const float* __restrict__ Whh,
                                               const float* __restrict__ h0,
                                               float* __restrict__ ZO,   // d_out: Z in, out overwrites
                                               ull* __restrict__ hb2)    // ws: 2*NW tagged words
{
  __shared__ uint4 hsb[2][DIMS / 8];     // double-buffered packed-bf16 h, swizzled
  __shared__ float zbuf[CHUNK][RPB];     // Z rows for current chunk
  __shared__ float xbuf[CHUNK][RPB];     // X rows for current chunk
  __shared__ float obuf[CHUNK][RPB];     // outputs of current chunk

  const int tid = threadIdx.x;
  const int b   = blockIdx.x;
  const int r   = tid >> 5;        // 0..7   local row
  const int c   = tid & 31;        // 0..31  K-chunk (64 elems)
  const int brow = b * RPB;
  const int grow = brow + r;

  // ---- one-time: this thread's W_hh slice -> 8 uint4 of bf16 pairs ----
  uint4 wq[8];
  {
    const float* wrow = Whh + (size_t)grow * DIMS + c * 64;
#pragma unroll
    for (int m = 0; m < 8; ++m) {
      float4 a = *(const float4*)(wrow + m * 8);
      float4 d = *(const float4*)(wrow + m * 8 + 4);
      wq[m] = make_uint4(pk_bf16(a.x, a.y), pk_bf16(a.z, a.w),
                         pk_bf16(d.x, d.y), pk_bf16(d.z, d.w));
    }
  }

  // ---- publish h0 as tagged words (tag 0) into slot 1 ----
  if (tid < 4) {
    unsigned pair = pk_bf16(h0[brow + 2 * tid], h0[brow + 2 * tid + 1]);
    __hip_atomic_store(&hb2[NW + b * 4 + tid], (ull)pair,
                       __ATOMIC_RELAXED, __HIP_MEMORY_SCOPE_AGENT);
  }

  for (int T = 0; T < SEQ; T += CHUNK) {
    // ---- chunk boundary: flush prev outputs, load this chunk's Z and X ----
    __syncthreads();   // obuf writes of prev chunk visible; zbuf/xbuf reads done
    if (tid < 32) {
      if (T > 0) {
        int s = tid >> 1, col = (tid & 1) * 4;
        *(float4*)&ZO[(size_t)(T - CHUNK + s) * DIMS + brow + col] =
            *(float4*)&obuf[s][col];
      }
    } else if (tid < 64) {
      int q = tid - 32, s = q >> 1, col = (q & 1) * 4;
      *(float4*)&zbuf[s][col] =
          *(const float4*)&ZO[(size_t)(T + s) * DIMS + brow + col];
    } else if (tid < 96) {
      int q = tid - 64, s = q >> 1, col = (q & 1) * 4;
      *(float4*)&xbuf[s][col] =
          *(const float4*)&X[(size_t)(T + s) * DIMS + brow + col];
    }
    __syncthreads();   // zbuf/xbuf staged (compiler waits vm before ds_write)

    for (int s = 0; s < CHUNK; ++s) {
      const int t = T + s;

      // ---- poll own 4 tagged words; data arrives WITH detection ----
      const ull* src = hb2 + (size_t)((t + 1) & 1) * NW + tid * 4;
      const unsigned want = (unsigned)t;
      v4u p01, p23;
      do {
        asm volatile(
            "global_load_dwordx4 %0, %2, off sc0 sc1\n\t"
            "global_load_dwordx4 %1, %3, off sc0 sc1\n\t"
            "s_waitcnt vmcnt(0)"
            : "=&v"(p01), "=&v"(p23)
            : "v"(src), "v"(src + 2)
            : "memory");
      } while (p01.y != want || p01.w != want || p23.y != want || p23.w != want);

      // ---- stage packed dwords into LDS (swizzled, double-buffered) ----
      {
        const int c0 = tid >> 3, m0 = tid & 7;
        hsb[t & 1][c0 * 8 + (m0 ^ (c0 & 7))] =
            make_uint4(p01.x, p01.z, p23.x, p23.z);
      }
      __syncthreads();   // the ONLY barrier per step

      // z/x for this step from LDS (no VMEM)
      float zcur = 0.f, xcur = 0.f;
      if (c == 0) { zcur = zbuf[s][r]; xcur = xbuf[s][r]; }

      // ---- matvec: row `grow`, K-slice [64c, 64c+64), bf16 x bf16 ----
      float acc = 0.f;
#pragma unroll
      for (int m = 0; m < 8; ++m) {
        uint4 w = wq[m];
        uint4 h = hsb[t & 1][c * 8 + (m ^ (c & 7))];
        acc += bflo(w.x) * bflo(h.x) + bfhi(w.x) * bfhi(h.x);
        acc += bflo(w.y) * bflo(h.y) + bfhi(w.y) * bfhi(h.y);
        acc += bflo(w.z) * bflo(h.z) + bfhi(w.z) * bfhi(h.z);
        acc += bflo(w.w) * bflo(h.w) + bfhi(w.w) * bfhi(h.w);
      }
#pragma unroll
      for (int off = 16; off > 0; off >>= 1) acc += __shfl_xor(acc, off);

      float hcur = 0.f;
      if (c == 0) hcur = tanhf(acc + zcur);   // lanes 0 and 32 of each wave
      float hhi = __shfl(hcur, 32);           // lane0 gets lane32's row
      if ((tid & 63) == 0) {
        // publish this wave's 2 rows: one tagged 8B store, nothing in front
        ull pk = ((ull)(unsigned)(t + 1) << 32) | (ull)pk_bf16(hcur, hhi);
        __hip_atomic_store(&hb2[(size_t)(t & 1) * NW + b * 4 + (tid >> 6)], pk,
                           __ATOMIC_RELAXED, __HIP_MEMORY_SCOPE_AGENT);
      }
      // residual into LDS (flushed at next boundary) — no VMEM
      if (c == 0) obuf[s][r] = xcur + hcur;
    }
  }

  // ---- epilogue: flush last chunk's outputs ----
  __syncthreads();
  if (tid < 32) {
    int s = tid >> 1, col = (tid & 1) * 4;
    *(float4*)&ZO[(size_t)(SEQ - CHUNK + s) * DIMS + brow + col] =
        *(float4*)&obuf[s][col];
  }
}

// ---------- launch ----------
extern "C" void kernel_launch(void* const* d_in, const int* in_sizes, int n_in,
                              void* d_out, int out_size, void* d_ws, size_t ws_size,
                              hipStream_t stream) {
  (void)in_sizes; (void)n_in; (void)out_size; (void)ws_size;
  const float* X    = (const float*)d_in[0];
  const float* Whi  = (const float*)d_in[1];
  const float* Whh  = (const float*)d_in[2];
  const float* bias = (const float*)d_in[3];
  const float* h0   = (const float*)d_in[4];
  float* out = (float*)d_out;

  ull* hb2 = (ull*)d_ws;   // 2*NW tagged words = 16 KB

  // tag bytes 0xFF never match any step tag -> replay-safe
  hipMemsetAsync(hb2, 0xFF, 2 * NW * sizeof(ull), stream);

  dim3 g(SEQ / 64, DIMS / 64);
  gemm_z<<<g, 256, 0, stream>>>(X, Whi, bias, out);
  rnn_seq<<<NBLK, 256, 0, stream>>>(X, Whh, h0, out, hb2);
}

// Round 8
// 10850.166 us; speedup vs baseline: 1.6355x; 1.6355x over previous
//
#include <hip/hip_runtime.h>
#include <hip/hip_bf16.h>
#include <stdint.h>

#define DIMS 2048
#define SEQ  4096
#define NBLK 256   // persistent blocks (one per CU); also = #producers = #K-slices
#define RPB  8     // rows of W_hh per block
#define NW   1024  // tagged words per slot (= DIMS/2)

typedef unsigned long long ull;
typedef unsigned int v4u __attribute__((ext_vector_type(4)));

// ---------- helpers ----------
__device__ __forceinline__ unsigned pk_bf16(float a, float b) {
  // round-to-nearest-even bf16, packed (a -> low16, b -> high16)
  unsigned ua = __float_as_uint(a);
  ua += 0x7fffu + ((ua >> 16) & 1u);
  unsigned ub = __float_as_uint(b);
  ub += 0x7fffu + ((ub >> 16) & 1u);
  return (ua >> 16) | (ub & 0xffff0000u);
}
__device__ __forceinline__ float bflo(unsigned u) { return __uint_as_float(u << 16); }
__device__ __forceinline__ float bfhi(unsigned u) { return __uint_as_float(u & 0xffff0000u); }

// ---------- Kernel A: Z = X @ W_hi^T + b  (fp32, written into d_out) ----------
__global__ __launch_bounds__(256) void gemm_z(const float* __restrict__ X,
                                              const float* __restrict__ W,
                                              const float* __restrict__ bias,
                                              float* __restrict__ Z) {
  __shared__ float xs[64][33];
  __shared__ float ws[64][33];
  const int tid = threadIdx.x;
  const int tx = tid & 15;
  const int ty = tid >> 4;
  const int s0 = blockIdx.x * 64;
  const int d0 = blockIdx.y * 64;

  float acc[4][4] = {};

  for (int k0 = 0; k0 < DIMS; k0 += 32) {
#pragma unroll
    for (int i = 0; i < 2; ++i) {
      int idx = tid + i * 256;
      int r = idx >> 3;
      int c = (idx & 7) << 2;
      float4 xv = *(const float4*)&X[(size_t)(s0 + r) * DIMS + k0 + c];
      xs[r][c] = xv.x; xs[r][c + 1] = xv.y; xs[r][c + 2] = xv.z; xs[r][c + 3] = xv.w;
      float4 wv = *(const float4*)&W[(size_t)(d0 + r) * DIMS + k0 + c];
      ws[r][c] = wv.x; ws[r][c + 1] = wv.y; ws[r][c + 2] = wv.z; ws[r][c + 3] = wv.w;
    }
    __syncthreads();
#pragma unroll
    for (int k = 0; k < 32; ++k) {
      float a_[4], b_[4];
#pragma unroll
      for (int i = 0; i < 4; ++i) a_[i] = xs[ty * 4 + i][k];
#pragma unroll
      for (int j = 0; j < 4; ++j) b_[j] = ws[tx * 4 + j][k];
#pragma unroll
      for (int i = 0; i < 4; ++i)
#pragma unroll
        for (int j = 0; j < 4; ++j) acc[i][j] += a_[i] * b_[j];
    }
    __syncthreads();
  }

  const float4 bv = *(const float4*)&bias[d0 + tx * 4];
#pragma unroll
  for (int i = 0; i < 4; ++i) {
    float4 o;
    o.x = acc[i][0] + bv.x; o.y = acc[i][1] + bv.y;
    o.z = acc[i][2] + bv.z; o.w = acc[i][3] + bv.w;
    *(float4*)&Z[(size_t)(s0 + ty * 4 + i) * DIMS + d0 + tx * 4] = o;
  }
}

// ---------- Kernel B: persistent recurrence, per-thread partial MACs ----------
// Consumer thread tid's polled 32B == producer block tid's K-slice h[8tid..8tid+8).
// On detect, the thread immediately MACs its slice against its 8 W-rows in VGPRs:
// NO h LDS stage, NO pre-MAC barrier, NO ds_read in the matvec.
// Reduce: butterfly xor{1,2,4} over 8 accs -> lane keeps row lane&7 -> xor{8,16,32}
// -> lanes 0..7 of each wave hold wave-sums -> tiny LDS wsum (double-buffered)
// -> ONE barrier -> wave0 lanes 0..7 finalize (sum4 + z, tanh) and publish the
// same tagged 8B words as R5. ZO store + next Z/X prefetch after publish (R5
// pattern, per-step uniform — no chunking, per R6's lesson).
// Slot safety: block publishes tag t+1 only after passing barrier(t), i.e. all
// its threads detected tag t; so when any block publishes t+1 (overwriting
// tag t-1 words), no thread anywhere still wants tag t-1. Same induction as R5.
__global__ __launch_bounds__(256) void rnn_seq(const float* __restrict__ X,
                                               const float* __restrict__ Whh,
                                               const float* __restrict__ h0,
                                               float* __restrict__ ZO,   // d_out: Z in, out overwrites
                                               ull* __restrict__ hb2)    // ws: 2*NW tagged words
{
  __shared__ float wsum[2][4][RPB];   // [t&1][wave][row] — 256 B total

  const int tid  = threadIdx.x;
  const int b    = blockIdx.x;
  const int lane = tid & 63;
  const int w    = tid >> 6;
  const int brow = b * RPB;

  // ---- one-time: W_hh rows for this block, K-slice [8*tid, 8*tid+8) ----
  // wq[r] dword d = bf16 pair (W[brow+r][8tid+2d], W[brow+r][8tid+2d+1])
  uint4 wq[8];
#pragma unroll
  for (int r = 0; r < RPB; ++r) {
    const float* wrow = Whh + (size_t)(brow + r) * DIMS + tid * 8;
    float4 a = *(const float4*)wrow;
    float4 d = *(const float4*)(wrow + 4);
    wq[r] = make_uint4(pk_bf16(a.x, a.y), pk_bf16(a.z, a.w),
                       pk_bf16(d.x, d.y), pk_bf16(d.z, d.w));
  }

  // ---- publish h0 as tagged words (tag 0) into slot 1 ----
  if (tid < 4) {
    unsigned pair = pk_bf16(h0[brow + 2 * tid], h0[brow + 2 * tid + 1]);
    __hip_atomic_store(&hb2[NW + b * 4 + tid], (ull)pair,
                       __ATOMIC_RELAXED, __HIP_MEMORY_SCOPE_AGENT);
  }
  // finalize lanes (tid 0..7) own row brow+tid: prefetch first-step Z/X
  float zpre = 0.f, xpre = 0.f;
  if (tid < RPB) { zpre = ZO[brow + tid]; xpre = X[brow + tid]; }

  for (int t = 0; t < SEQ; ++t) {
    // ---- poll own 4 tagged words (producer block `tid`); data rides along ----
    const ull* src = hb2 + (size_t)((t + 1) & 1) * NW + tid * 4;
    const unsigned want = (unsigned)t;
    v4u p01, p23;
    do {
      asm volatile(
          "global_load_dwordx4 %0, %2, off sc0 sc1\n\t"
          "global_load_dwordx4 %1, %3, off sc0 sc1\n\t"
          "s_waitcnt vmcnt(0)"
          : "=&v"(p01), "=&v"(p23)
          : "v"(src), "v"(src + 2)
          : "memory");
    } while (p01.y != want || p01.w != want || p23.y != want || p23.w != want);

    // ---- immediate per-thread MACs: 8 rows x 8 K-elems, no LDS, no barrier ----
    float hf[8];
    {
      unsigned hd0 = p01.x, hd1 = p01.z, hd2 = p23.x, hd3 = p23.z;
      hf[0] = bflo(hd0); hf[1] = bfhi(hd0);
      hf[2] = bflo(hd1); hf[3] = bfhi(hd1);
      hf[4] = bflo(hd2); hf[5] = bfhi(hd2);
      hf[6] = bflo(hd3); hf[7] = bfhi(hd3);
    }
    float acc[8];
#pragma unroll
    for (int r = 0; r < RPB; ++r) {
      uint4 q = wq[r];
      acc[r] = bflo(q.x) * hf[0] + bfhi(q.x) * hf[1]
             + bflo(q.y) * hf[2] + bfhi(q.y) * hf[3]
             + bflo(q.z) * hf[4] + bfhi(q.z) * hf[5]
             + bflo(q.w) * hf[6] + bfhi(q.w) * hf[7];
    }

    // ---- in-wave reduce: xor{1,2,4} butterfly, select row lane&7, xor{8,16,32} ----
#pragma unroll
    for (int off = 1; off <= 4; off <<= 1)
#pragma unroll
      for (int r = 0; r < RPB; ++r) acc[r] += __shfl_xor(acc[r], off);
    const int rr = lane & 7;
    float v = acc[0];
    v = (rr == 1) ? acc[1] : v;
    v = (rr == 2) ? acc[2] : v;
    v = (rr == 3) ? acc[3] : v;
    v = (rr == 4) ? acc[4] : v;
    v = (rr == 5) ? acc[5] : v;
    v = (rr == 6) ? acc[6] : v;
    v = (rr == 7) ? acc[7] : v;
#pragma unroll
    for (int off = 8; off <= 32; off <<= 1) v += __shfl_xor(v, off);

    // ---- cross-wave: lanes 0..7 deposit wave-sums; ONE barrier ----
    if (lane < RPB) wsum[t & 1][w][lane] = v;
    __syncthreads();

    // ---- finalize on wave0 lanes 0..7 (row brow+tid) ----
    if (tid < RPB) {
      float s = wsum[t & 1][0][tid] + wsum[t & 1][1][tid]
              + wsum[t & 1][2][tid] + wsum[t & 1][3][tid];
      float hcur = tanhf(s + zpre);
      float hnxt = __shfl_xor(hcur, 1);      // lanes 0..7 all active
      if ((tid & 1) == 0) {
        // publish tagged word (h[2g] lo, h[2g+1] hi | tag t+1) — same as R5
        ull pk = ((ull)(unsigned)(t + 1) << 32) | (ull)pk_bf16(hcur, hnxt);
        __hip_atomic_store(&hb2[(size_t)(t & 1) * NW + b * 4 + (tid >> 1)], pk,
                           __ATOMIC_RELAXED, __HIP_MEMORY_SCOPE_AGENT);
      }
      // off-critical-path: residual out + next-step Z/X prefetch (per-step uniform)
      ZO[(size_t)t * DIMS + brow + tid] = xpre + hcur;
      if (t + 1 < SEQ) {
        zpre = ZO[(size_t)(t + 1) * DIMS + brow + tid];
        xpre = X[(size_t)(t + 1) * DIMS + brow + tid];
      }
    }
  }
}

// ---------- launch ----------
extern "C" void kernel_launch(void* const* d_in, const int* in_sizes, int n_in,
                              void* d_out, int out_size, void* d_ws, size_t ws_size,
                              hipStream_t stream) {
  (void)in_sizes; (void)n_in; (void)out_size; (void)ws_size;
  const float* X    = (const float*)d_in[0];
  const float* Whi  = (const float*)d_in[1];
  const float* Whh  = (const float*)d_in[2];
  const float* bias = (const float*)d_in[3];
  const float* h0   = (const float*)d_in[4];
  float* out = (float*)d_out;

  ull* hb2 = (ull*)d_ws;   // 2*NW tagged words = 16 KB

  // tag bytes 0xFF never match any step tag -> replay-safe
  hipMemsetAsync(hb2, 0xFF, 2 * NW * sizeof(ull), stream);

  dim3 g(SEQ / 64, DIMS / 64);
  gemm_z<<<g, 256, 0, stream>>>(X, Whi, bias, out);
  rnn_seq<<<NBLK, 256, 0, stream>>>(X, Whh, h0, out, hb2);
}